// Round 11
// baseline (426.988 us; speedup 1.0000x reference)
//
#include <hip/hip_runtime.h>
#include <hip/hip_cooperative_groups.h>

namespace cg = cooperative_groups;

#define N_PTS 20000
#define DIMS  128
#define A_CNT 1024
#define KNEG  10
#define NTILES 157              // ceil(20000/128)
#define NCHUNK (NTILES * 16)    // 2512 chunk-of-8 slots per (side, anchor)
#define NCHUNK_REAL 2500        // 20000/8 — chunks >=2500 are pure padding
#define BIGV  1e18f
#define BIGI  0x7F000000
#define CAND_CAP 768
#define PT_CAP   768
#define AB_BLOCKS 1024          // absmax partial slots (fallback grid / coop cap)
#define QR_BLOCKS 625           // quantR virtual x-grid; 625*256/8 = 20000 rows
#define RPART     1250          // quantR partial-Rmax slots (625 * 2 sides)

// v_sad_u8: d = c + sum_{i=0..3} |a.byte[i] - b.byte[i]|  (4 dims per VALU op)
__device__ __forceinline__ unsigned int sad_u8(unsigned int a, unsigned int b, unsigned int c) {
#if __has_builtin(__builtin_amdgcn_sad_u8)
    return __builtin_amdgcn_sad_u8(a, b, c);
#else
    unsigned int d;
    asm("v_sad_u8 %0, %1, %2, %3" : "=v"(d) : "v"(a), "v"(b), "v"(c));
    return d;
#endif
}

// ===========================================================================
// FALLBACK PATH: the proven 4-dispatch chain (R9 config, 208us, passes).
// ===========================================================================
__global__ void absmax_kernel(const float* __restrict__ a, const float* __restrict__ b,
                              float* __restrict__ wsAmax, float* __restrict__ outZero) {
    __shared__ float sm[4];
    const int n4 = N_PTS * DIMS / 4;
    const int stride = gridDim.x * blockDim.x;
    float m = 0.f;
    for (int i = blockIdx.x * blockDim.x + threadIdx.x; i < 2 * n4; i += stride) {
        const float4 v = (i < n4) ? ((const float4*)a)[i] : ((const float4*)b)[i - n4];
        m = fmaxf(m, fmaxf(fmaxf(fabsf(v.x), fabsf(v.y)), fmaxf(fabsf(v.z), fabsf(v.w))));
    }
#pragma unroll
    for (int s = 1; s < 64; s <<= 1) m = fmaxf(m, __shfl_xor(m, s, 64));
    if ((threadIdx.x & 63) == 0) sm[threadIdx.x >> 6] = m;
    __syncthreads();
    if (threadIdx.x == 0) {
        wsAmax[blockIdx.x] = fmaxf(fmaxf(sm[0], sm[1]), fmaxf(sm[2], sm[3]));
        if (blockIdx.x == 0) *outZero = 0.f;
    }
}

__global__ void quantR_kernel(const float* __restrict__ o1, const float* __restrict__ o2,
                              unsigned int* __restrict__ q1, unsigned int* __restrict__ q2,
                              float* __restrict__ Ra, float* __restrict__ Rb,
                              const float* __restrict__ wsAmax,
                              float* __restrict__ wsRmaxPart) {
    __shared__ float sm[4];
    __shared__ float sM;
    const int tid = threadIdx.x;
    {
        const float4 v = ((const float4*)wsAmax)[tid];     // 256 * 4 = 1024
        float m = fmaxf(fmaxf(v.x, v.y), fmaxf(v.z, v.w));
#pragma unroll
        for (int s = 1; s < 64; s <<= 1) m = fmaxf(m, __shfl_xor(m, s, 64));
        if ((tid & 63) == 0) sm[tid >> 6] = m;
        __syncthreads();
        if (tid == 0) sM = fmaxf(fmaxf(sm[0], sm[1]), fmaxf(sm[2], sm[3]));
        __syncthreads();
    }
    const float M = sM;
    const float s = 127.0f / M;

    const int side = blockIdx.y;
    const float* src = side ? o2 : o1;
    unsigned int* dst = side ? q2 : q1;
    float* Rrow = side ? Rb : Ra;
    const int g = blockIdx.x * 256 + tid;
    const int row = g >> 3;
    const int sub = g & 7;
    const float4* s4 = (const float4*)(src + (size_t)row * DIMS + sub * 16);
    unsigned int* d = dst + (size_t)row * 32 + sub * 4;
    float rs = 0.f;
#pragma unroll
    for (int m4 = 0; m4 < 4; ++m4) {
        const float4 v = s4[m4];
        const float f0 = v.x * s + 127.0f, f1 = v.y * s + 127.0f;
        const float f2 = v.z * s + 127.0f, f3 = v.w * s + 127.0f;
        const float q0 = rintf(f0), q1v = rintf(f1), q2v = rintf(f2), q3 = rintf(f3);
        rs += fabsf(q0 - f0) + fabsf(q1v - f1) + fabsf(q2v - f2) + fabsf(q3 - f3);
        d[m4] = (unsigned int)q0 | ((unsigned int)q1v << 8) |
                ((unsigned int)q2v << 16) | ((unsigned int)q3 << 24);
    }
    rs += __shfl_xor(rs, 1, 64);
    rs += __shfl_xor(rs, 2, 64);
    rs += __shfl_xor(rs, 4, 64);
    const float R = rs + 1.0f;
    if (sub == 0) Rrow[row] = R;
    float rm = R;
    rm = fmaxf(rm, __shfl_xor(rm, 8, 64));
    rm = fmaxf(rm, __shfl_xor(rm, 16, 64));
    rm = fmaxf(rm, __shfl_xor(rm, 32, 64));
    if ((tid & 63) == 0) sm[tid >> 6] = rm;
    __syncthreads();
    if (tid == 0)
        wsRmaxPart[blockIdx.y * QR_BLOCKS + blockIdx.x] =
            fmaxf(fmaxf(sm[0], sm[1]), fmaxf(sm[2], sm[3]));
}

__global__ __launch_bounds__(256, 4)
void dist_sad_kernel(const unsigned int* __restrict__ q1, const unsigned int* __restrict__ q2,
                     const int* __restrict__ anchor1, const int* __restrict__ anchor2,
                     unsigned short* __restrict__ minOut,
                     const float* __restrict__ wsRmaxPart, float* __restrict__ rmaxOut) {
    __shared__ unsigned int sP[128 * 32];
    const int tile = blockIdx.x;
    const int ag   = blockIdx.y;
    const int side = blockIdx.z;

    if (tile == 0 && ag == 0 && side == 0 && threadIdx.x < 64) {
        float r = 0.f;
        for (int i = threadIdx.x; i < RPART; i += 64) r = fmaxf(r, wsRmaxPart[i]);
#pragma unroll
        for (int s = 1; s < 64; s <<= 1) r = fmaxf(r, __shfl_xor(r, s, 64));
        if (threadIdx.x == 0) *rmaxOut = r;
    }

    const unsigned int* aData = side ? q2 : q1;
    const unsigned int* pData = side ? q1 : q2;
    const int*          aIdx  = side ? anchor2 : anchor1;
    const int tid = threadIdx.x;
    const int tx = tid & 15;
    const int ty = tid >> 4;

    const int4 aidx4 = ((const int4*)(aIdx + ag * 64))[ty];
    const unsigned int* aRow0 = aData + (size_t)aidx4.x * 32;
    const unsigned int* aRow1 = aData + (size_t)aidx4.y * 32;
    const unsigned int* aRow2 = aData + (size_t)aidx4.z * 32;
    const unsigned int* aRow3 = aData + (size_t)aidx4.w * 32;

    {
        const int rp = tid >> 1;
        const int h  = tid & 1;
        const int prow = tile * 128 + rp;
        const bool pvalid = prow < N_PTS;
        const uint4* pRow4 = (const uint4*)(pData + (size_t)prow * 32 + h * 16);
        const int rot = rp >> 3;
#pragma unroll
        for (int j = 0; j < 4; ++j) {
            const uint4 v = pvalid ? pRow4[j]
                                   : make_uint4(0xFFFFFFFFu, 0xFFFFFFFFu, 0xFFFFFFFFu, 0xFFFFFFFFu);
            const int blk = h * 4 + j;
            *(uint4*)&sP[rp * 32 + (((blk + rot) & 7) << 2)] = v;
        }
    }
    __syncthreads();

    unsigned int acc[4][8];
#pragma unroll
    for (int i = 0; i < 4; ++i)
#pragma unroll
        for (int j = 0; j < 8; ++j) acc[i][j] = 0u;
    const int tx8 = tx * 8;

#pragma unroll 2
    for (int bk = 0; bk < 8; ++bk) {
        uint4 A[4], P[8];
        A[0] = *(const uint4*)(aRow0 + bk * 4);
        A[1] = *(const uint4*)(aRow1 + bk * 4);
        A[2] = *(const uint4*)(aRow2 + bk * 4);
        A[3] = *(const uint4*)(aRow3 + bk * 4);
        const int pslot = ((bk + tx) & 7) << 2;
#pragma unroll
        for (int j = 0; j < 8; ++j) P[j] = *(const uint4*)&sP[(tx8 + j) * 32 + pslot];
#pragma unroll
        for (int i = 0; i < 4; ++i)
#pragma unroll
            for (int j = 0; j < 8; ++j) {
                unsigned int s = sad_u8(A[i].x, P[j].x, acc[i][j]);
                s = sad_u8(A[i].y, P[j].y, s);
                s = sad_u8(A[i].z, P[j].z, s);
                acc[i][j] = sad_u8(A[i].w, P[j].w, s);
            }
    }

    const int ty4 = ty * 4;
    const size_t outBase = (size_t)side * A_CNT * NCHUNK;
#pragma unroll
    for (int i = 0; i < 4; ++i) {
        unsigned int m = min(min(min(acc[i][0], acc[i][1]), min(acc[i][2], acc[i][3])),
                             min(min(acc[i][4], acc[i][5]), min(acc[i][6], acc[i][7])));
        minOut[outBase + (size_t)(ag * 64 + ty4 + i) * NCHUNK + tile * 16 + tx] =
            (unsigned short)m;
    }
}

__global__ __launch_bounds__(256, 4)
void select_kernel(const float* __restrict__ out1, const float* __restrict__ out2,
                   const unsigned int* __restrict__ q1, const unsigned int* __restrict__ q2,
                   const int* __restrict__ anchor1, const int* __restrict__ anchor2,
                   const unsigned short* __restrict__ minIn,
                   const float* __restrict__ R1, const float* __restrict__ R2,
                   const float* __restrict__ rmaxIn, float* __restrict__ out) {
    const int bid = blockIdx.x;
    const int side = bid >> 10;
    const int ai = bid & 1023;
    const int tid = threadIdx.x;
    const int lane = tid & 63;
    const int wv = tid >> 6;

    const float* aDataF = side ? out2 : out1;
    const float* pDataF = side ? out1 : out2;
    const unsigned int* aDataQ = side ? q2 : q1;
    const unsigned int* pDataQ = side ? q1 : q2;
    const float* Ranc = side ? R2 : R1;
    const int* aIdx = side ? anchor2 : anchor1;

    __shared__ int candCount, pointCount;
    __shared__ int candList[CAND_CAP];
    __shared__ int ptList[PT_CAP];
    __shared__ __align__(16) float sDist[PT_CAP];
    __shared__ int sMin[4];
    __shared__ int sCnt[4];
    __shared__ float wSum[4];
    __shared__ float sDm;

    const int arow = aIdx[ai];
    const uint4 qa4 = ((const uint4*)(aDataQ + (size_t)arow * 32))[lane & 7];
    if (tid == 0) { candCount = 0; pointCount = 0; }

    if (wv == 0) {
        const int r1 = anchor1[ai], r2 = anchor2[ai];
        const float2 x1 = ((const float2*)(out1 + (size_t)r1 * DIMS))[lane];
        const float2 x2 = ((const float2*)(out2 + (size_t)r2 * DIMS))[lane];
        float dm = fabsf(x1.x - x2.x) + fabsf(x1.y - x2.y);
#pragma unroll
        for (int s = 1; s < 64; s <<= 1) dm += __shfl_xor(dm, s, 64);
        if (lane == 0) sDm = dm + 1.0f;
    }

    const unsigned short* mbase = minIn + ((size_t)side * A_CNT + ai) * NCHUNK;
    int mv[10];
#pragma unroll
    for (int j = 0; j < 10; ++j) {
        const int c = tid + 256 * j;
        mv[j] = (c < NCHUNK_REAL) ? (int)mbase[c] : BIGI;
    }
    int lmin = BIGI;
#pragma unroll
    for (int j = 0; j < 10; ++j) lmin = min(lmin, mv[j]);
#pragma unroll
    for (int s = 1; s < 64; s <<= 1) lmin = min(lmin, __shfl_xor(lmin, s, 64));
    if (lane == 0) sMin[wv] = lmin;
    __syncthreads();
    const int m1 = min(min(sMin[0], sMin[1]), min(sMin[2], sMin[3]));

    int E = m1 + 192;
    for (;;) {
        int c = 0;
#pragma unroll
        for (int j = 0; j < 10; ++j) c += (mv[j] <= E) ? 1 : 0;
#pragma unroll
        for (int s = 1; s < 64; s <<= 1) c += __shfl_xor(c, s, 64);
        if (lane == 0) sCnt[wv] = c;
        __syncthreads();
        const int total = sCnt[0] + sCnt[1] + sCnt[2] + sCnt[3];
        __syncthreads();
        if (total >= KNEG) break;
        E += 192;
    }
    int lo = (E == m1 + 192) ? (m1 - 1) : (E - 192);
    int hi = E;
#pragma unroll
    for (int it = 0; it < 3; ++it) {
        const int mid = (lo + hi) >> 1;
        int c = 0;
#pragma unroll
        for (int j = 0; j < 10; ++j) c += (mv[j] <= mid) ? 1 : 0;
#pragma unroll
        for (int s = 1; s < 64; s <<= 1) c += __shfl_xor(c, s, 64);
        if (lane == 0) sCnt[wv] = c;
        __syncthreads();
        const int total = sCnt[0] + sCnt[1] + sCnt[2] + sCnt[3];
        __syncthreads();
        if (total >= KNEG) hi = mid; else lo = mid;
    }
    const float Rmax = *rmaxIn;
    const float thr = (float)hi + 2.0f * Ranc[arow] + 2.0f * Rmax + 4.0f;

#pragma unroll
    for (int j = 0; j < 10; ++j) {
        const int c = tid + 256 * j;
        if (c < NCHUNK_REAL && (float)mv[j] <= thr) {
            const int pos = atomicAdd(&candCount, 1);
            if (pos < CAND_CAP) candList[pos] = c;
        }
    }
    __syncthreads();
    const int cc = min(candCount, CAND_CAP);

    const int psub = lane >> 3;
    const int seg  = lane & 7;
    for (int s0 = wv * 4; s0 < cc; s0 += 16) {
        uint4 qp[4];
        int ptv[4];
#pragma unroll
        for (int u = 0; u < 4; ++u) {
            const int s = s0 + u;
            const int c = candList[(s < cc) ? s : s0];
            ptv[u] = c * 8 + psub;
            qp[u] = ((const uint4*)(pDataQ + (size_t)ptv[u] * 32))[seg];
        }
#pragma unroll
        for (int u = 0; u < 4; ++u) {
            unsigned int d = sad_u8(qa4.x, qp[u].x, 0u);
            d = sad_u8(qa4.y, qp[u].y, d);
            d = sad_u8(qa4.z, qp[u].z, d);
            d = sad_u8(qa4.w, qp[u].w, d);
            int di = (int)d;
            di += __shfl_xor(di, 1, 64);
            di += __shfl_xor(di, 2, 64);
            di += __shfl_xor(di, 4, 64);
            if ((s0 + u) < cc && seg == 0 && (float)di <= thr) {
                const int pos = atomicAdd(&pointCount, 1);
                if (pos < PT_CAP) ptList[pos] = ptv[u];
            }
        }
    }
    __syncthreads();
    const int pc = min(pointCount, PT_CAP);

    const int pt4 = tid >> 2;
    const int qq  = tid & 3;
    float4 av[8];
    {
        const float4* aF4 = (const float4*)(aDataF + (size_t)arow * DIMS) + qq * 8;
#pragma unroll
        for (int q = 0; q < 8; ++q) av[q] = aF4[q];
    }
    for (int base = 0; base < pc; base += 64) {
        const int idx = base + pt4;
        float s01 = 0.f, s23 = 0.f;
        if (idx < pc) {
            const int pt = ptList[idx];
            const float4* p4 = (const float4*)(pDataF + (size_t)pt * DIMS) + qq * 8;
#pragma unroll
            for (int q = 0; q < 8; ++q) {
                const float4 pv = p4[q];
                s01 += fabsf(av[q].x - pv.x) + fabsf(av[q].y - pv.y);
                s23 += fabsf(av[q].z - pv.z) + fabsf(av[q].w - pv.w);
            }
        }
        float s = s01 + s23;
        s += __shfl_xor(s, 1, 64);
        s += __shfl_xor(s, 2, 64);
        if (qq == 0 && idx < pc) sDist[idx] = s;
    }
    __syncthreads();

    const float dm = sDm;
    float contrib = 0.f;
    if (pc <= 256) {
        const int i0 = tid;
        const float v = (i0 < pc) ? sDist[i0] : BIGV;
        int r0 = 0;
        int j = 0;
        for (; j + 2 <= pc; j += 2) {
            const float2 vj = *(const float2*)&sDist[j];
            r0 += ((vj.x < v) || (vj.x == v && j < i0)) ? 1 : 0;
            r0 += ((vj.y < v) || (vj.y == v && (j + 1) < i0)) ? 1 : 0;
        }
        if (j < pc) {
            const float vj = sDist[j];
            r0 += ((vj < v) || (vj == v && j < i0)) ? 1 : 0;
        }
        if (i0 < pc && r0 < KNEG) contrib = fmaxf(dm - v, 0.f);
    } else {
        const int i0 = tid, i1 = tid + 256, i2 = tid + 512;
        float va = BIGV, vb = BIGV, vc = BIGV;
        if (i0 < pc) va = sDist[i0];
        if (i1 < pc) vb = sDist[i1];
        if (i2 < pc) vc = sDist[i2];
        int r0 = 0, r1 = 0, r2 = 0;
        for (int j = 0; j < pc; ++j) {
            const float vj = sDist[j];
            r0 += (vj < va) || (vj == va && j < i0);
            r1 += (vj < vb) || (vj == vb && j < i1);
            r2 += (vj < vc) || (vj == vc && j < i2);
        }
        if (i0 < pc && r0 < KNEG) contrib += fmaxf(dm - va, 0.f);
        if (i1 < pc && r1 < KNEG) contrib += fmaxf(dm - vb, 0.f);
        if (i2 < pc && r2 < KNEG) contrib += fmaxf(dm - vc, 0.f);
    }
#pragma unroll
    for (int s = 1; s < 64; s <<= 1) contrib += __shfl_xor(contrib, s, 64);
    if (lane == 0) wSum[wv] = contrib;
    __syncthreads();
    if (tid == 0)
        atomicAdd(out, (wSum[0] + wSum[1] + wSum[2] + wSum[3]) * (1.0f / (A_CNT * KNEG)));
}

// ===========================================================================
// COOP PATH: one fused kernel, grid-size-agnostic (all loops stride by
// gridDim.x), phase bodies identical to the fallback kernels above.
// ===========================================================================
__global__ __launch_bounds__(256, 4)
void fused_kernel(const float* __restrict__ out1, const float* __restrict__ out2,
                  const int* __restrict__ anchor1, const int* __restrict__ anchor2,
                  unsigned int* __restrict__ q1, unsigned int* __restrict__ q2,
                  unsigned short* __restrict__ minbuf,
                  float* __restrict__ R1, float* __restrict__ R2,
                  float* __restrict__ wsAmax, float* __restrict__ wsRmaxPart,
                  float* __restrict__ rmaxG, float* __restrict__ out) {
    cg::grid_group grid = cg::this_grid();
    const int bid = blockIdx.x;
    const int nb  = gridDim.x;
    const int tid = threadIdx.x;
    const int lane = tid & 63;
    const int wv = tid >> 6;

    __shared__ unsigned int sP[128 * 32];   // 16KB: dist_sad staging / select lists
    __shared__ float smax[4];
    __shared__ float sM;

    // ===== Phase 1: absmax partials; block 0 zeroes out =====
    {
        const int n4 = N_PTS * DIMS / 4;
        float m = 0.f;
        for (int i = bid * 256 + tid; i < 2 * n4; i += nb * 256) {
            const float4 v = (i < n4) ? ((const float4*)out1)[i] : ((const float4*)out2)[i - n4];
            m = fmaxf(m, fmaxf(fmaxf(fabsf(v.x), fabsf(v.y)), fmaxf(fabsf(v.z), fabsf(v.w))));
        }
#pragma unroll
        for (int s = 1; s < 64; s <<= 1) m = fmaxf(m, __shfl_xor(m, s, 64));
        if (lane == 0) smax[wv] = m;
        __syncthreads();
        if (tid == 0) {
            wsAmax[bid] = fmaxf(fmaxf(smax[0], smax[1]), fmaxf(smax[2], smax[3]));
            if (bid == 0) *out = 0.f;
        }
    }
    grid.sync();

    // ===== Phase 2: quantR (1250 virtual blocks) =====
    {
        __syncthreads();                     // smax reuse after phase 1
        {   // generic block-local reduce of the nb absmax partials
            float m = 0.f;
            for (int i = tid; i < nb; i += 256) m = fmaxf(m, wsAmax[i]);
#pragma unroll
            for (int s = 1; s < 64; s <<= 1) m = fmaxf(m, __shfl_xor(m, s, 64));
            if (lane == 0) smax[wv] = m;
            __syncthreads();
            if (tid == 0) sM = fmaxf(fmaxf(smax[0], smax[1]), fmaxf(smax[2], smax[3]));
            __syncthreads();
        }
        const float M = sM;
        const float s = 127.0f / M;
        for (int vb = bid; vb < 2 * QR_BLOCKS; vb += nb) {
            __syncthreads();                 // smax reuse across iterations
            const int side = (vb >= QR_BLOCKS) ? 1 : 0;
            const int bx = side ? (vb - QR_BLOCKS) : vb;
            const float* src = side ? out2 : out1;
            unsigned int* dst = side ? q2 : q1;
            float* Rrow = side ? R2 : R1;
            const int g = bx * 256 + tid;
            const int row = g >> 3;
            const int sub = g & 7;
            const float4* s4 = (const float4*)(src + (size_t)row * DIMS + sub * 16);
            unsigned int* d = dst + (size_t)row * 32 + sub * 4;
            float rs = 0.f;
#pragma unroll
            for (int m4 = 0; m4 < 4; ++m4) {
                const float4 v = s4[m4];
                const float f0 = v.x * s + 127.0f, f1 = v.y * s + 127.0f;
                const float f2 = v.z * s + 127.0f, f3 = v.w * s + 127.0f;
                const float q0 = rintf(f0), q1v = rintf(f1), q2v = rintf(f2), q3 = rintf(f3);
                rs += fabsf(q0 - f0) + fabsf(q1v - f1) + fabsf(q2v - f2) + fabsf(q3 - f3);
                d[m4] = (unsigned int)q0 | ((unsigned int)q1v << 8) |
                        ((unsigned int)q2v << 16) | ((unsigned int)q3 << 24);
            }
            rs += __shfl_xor(rs, 1, 64);
            rs += __shfl_xor(rs, 2, 64);
            rs += __shfl_xor(rs, 4, 64);
            const float R = rs + 1.0f;
            if (sub == 0) Rrow[row] = R;
            float rm = R;
            rm = fmaxf(rm, __shfl_xor(rm, 8, 64));
            rm = fmaxf(rm, __shfl_xor(rm, 16, 64));
            rm = fmaxf(rm, __shfl_xor(rm, 32, 64));
            if (lane == 0) smax[wv] = rm;
            __syncthreads();
            if (tid == 0)
                wsRmaxPart[side * QR_BLOCKS + bx] =
                    fmaxf(fmaxf(smax[0], smax[1]), fmaxf(smax[2], smax[3]));
        }
    }
    grid.sync();

    // ===== Phase 3: dist_sad (5024 virtual blocks) =====
    if (bid == 0 && tid < 64) {
        float r = 0.f;
        for (int i = tid; i < RPART; i += 64) r = fmaxf(r, wsRmaxPart[i]);
#pragma unroll
        for (int s = 1; s < 64; s <<= 1) r = fmaxf(r, __shfl_xor(r, s, 64));
        if (tid == 0) *rmaxG = r;
    }
    {
        const int tx = tid & 15;
        const int ty = tid >> 4;
        const int tx8 = tx * 8;
        const int ty4 = ty * 4;
        for (int vb = bid; vb < NTILES * 32; vb += nb) {
            const int tile = vb % NTILES;
            const int rest = vb / NTILES;    // 0..31
            const int ag   = rest & 15;
            const int side = rest >> 4;

            const unsigned int* aData = side ? q2 : q1;
            const unsigned int* pData = side ? q1 : q2;
            const int*          aIdx  = side ? anchor2 : anchor1;

            const int4 aidx4 = ((const int4*)(aIdx + ag * 64))[ty];
            const unsigned int* aRow0 = aData + (size_t)aidx4.x * 32;
            const unsigned int* aRow1 = aData + (size_t)aidx4.y * 32;
            const unsigned int* aRow2 = aData + (size_t)aidx4.z * 32;
            const unsigned int* aRow3 = aData + (size_t)aidx4.w * 32;

            __syncthreads();                 // protect sP from previous iteration
            {
                const int rp = tid >> 1;
                const int h  = tid & 1;
                const int prow = tile * 128 + rp;
                const bool pvalid = prow < N_PTS;
                const uint4* pRow4 = (const uint4*)(pData + (size_t)prow * 32 + h * 16);
                const int rot = rp >> 3;
#pragma unroll
                for (int j = 0; j < 4; ++j) {
                    const uint4 v = pvalid ? pRow4[j]
                                           : make_uint4(0xFFFFFFFFu, 0xFFFFFFFFu,
                                                        0xFFFFFFFFu, 0xFFFFFFFFu);
                    const int blk = h * 4 + j;
                    *(uint4*)&sP[rp * 32 + (((blk + rot) & 7) << 2)] = v;
                }
            }
            __syncthreads();

            unsigned int acc[4][8];
#pragma unroll
            for (int i = 0; i < 4; ++i)
#pragma unroll
                for (int j = 0; j < 8; ++j) acc[i][j] = 0u;

#pragma unroll 2
            for (int bk = 0; bk < 8; ++bk) {
                uint4 A[4], P[8];
                A[0] = *(const uint4*)(aRow0 + bk * 4);
                A[1] = *(const uint4*)(aRow1 + bk * 4);
                A[2] = *(const uint4*)(aRow2 + bk * 4);
                A[3] = *(const uint4*)(aRow3 + bk * 4);
                const int pslot = ((bk + tx) & 7) << 2;
#pragma unroll
                for (int j = 0; j < 8; ++j) P[j] = *(const uint4*)&sP[(tx8 + j) * 32 + pslot];
#pragma unroll
                for (int i = 0; i < 4; ++i)
#pragma unroll
                    for (int j = 0; j < 8; ++j) {
                        unsigned int sacc = sad_u8(A[i].x, P[j].x, acc[i][j]);
                        sacc = sad_u8(A[i].y, P[j].y, sacc);
                        sacc = sad_u8(A[i].z, P[j].z, sacc);
                        acc[i][j] = sad_u8(A[i].w, P[j].w, sacc);
                    }
            }

            const size_t outBase = (size_t)side * A_CNT * NCHUNK;
#pragma unroll
            for (int i = 0; i < 4; ++i) {
                unsigned int m = min(min(min(acc[i][0], acc[i][1]), min(acc[i][2], acc[i][3])),
                                     min(min(acc[i][4], acc[i][5]), min(acc[i][6], acc[i][7])));
                minbuf[outBase + (size_t)(ag * 64 + ty4 + i) * NCHUNK + tile * 16 + tx] =
                    (unsigned short)m;
            }
        }
    }
    grid.sync();

    // ===== Phase 4: select (2048 virtual tasks) =====
    {
        int* candList = (int*)sP;                       // ints 0..767
        int* ptList   = candList + CAND_CAP;            // 768..1535
        float* sDist  = (float*)(ptList + PT_CAP);      // 1536..2303 (byte 6144, 16B-aligned)
        int* misc     = (int*)(sDist + PT_CAP);
        // misc[0]=candCount [1]=pointCount [2..5]=sMin [6..9]=sCnt
        // (float)misc[10..13]=wSum  (float)misc[14]=sDm
        float* wSum = (float*)(misc + 10);
        const float Rmax = *rmaxG;

        for (int vt = bid; vt < 2 * A_CNT; vt += nb) {
            __syncthreads();                 // protect all shared reuse
            const int side = vt >> 10;
            const int ai = vt & 1023;

            const float* aDataF = side ? out2 : out1;
            const float* pDataF = side ? out1 : out2;
            const unsigned int* aDataQ = side ? q2 : q1;
            const unsigned int* pDataQ = side ? q1 : q2;
            const float* Ranc = side ? R2 : R1;
            const int* aIdx = side ? anchor2 : anchor1;

            const int arow = aIdx[ai];
            const uint4 qa4 = ((const uint4*)(aDataQ + (size_t)arow * 32))[lane & 7];
            if (tid == 0) { misc[0] = 0; misc[1] = 0; }

            if (wv == 0) {
                const int r1 = anchor1[ai], r2 = anchor2[ai];
                const float2 x1 = ((const float2*)(out1 + (size_t)r1 * DIMS))[lane];
                const float2 x2 = ((const float2*)(out2 + (size_t)r2 * DIMS))[lane];
                float dm = fabsf(x1.x - x2.x) + fabsf(x1.y - x2.y);
#pragma unroll
                for (int s = 1; s < 64; s <<= 1) dm += __shfl_xor(dm, s, 64);
                if (lane == 0) ((float*)misc)[14] = dm + 1.0f;
            }

            const unsigned short* mbase = minbuf + ((size_t)side * A_CNT + ai) * NCHUNK;
            int mv[10];
#pragma unroll
            for (int j = 0; j < 10; ++j) {
                const int c = tid + 256 * j;
                mv[j] = (c < NCHUNK_REAL) ? (int)mbase[c] : BIGI;
            }
            int lmin = BIGI;
#pragma unroll
            for (int j = 0; j < 10; ++j) lmin = min(lmin, mv[j]);
#pragma unroll
            for (int s = 1; s < 64; s <<= 1) lmin = min(lmin, __shfl_xor(lmin, s, 64));
            if (lane == 0) misc[2 + wv] = lmin;
            __syncthreads();
            const int m1 = min(min(misc[2], misc[3]), min(misc[4], misc[5]));

            int E = m1 + 192;
            for (;;) {
                int c = 0;
#pragma unroll
                for (int j = 0; j < 10; ++j) c += (mv[j] <= E) ? 1 : 0;
#pragma unroll
                for (int s = 1; s < 64; s <<= 1) c += __shfl_xor(c, s, 64);
                if (lane == 0) misc[6 + wv] = c;
                __syncthreads();
                const int total = misc[6] + misc[7] + misc[8] + misc[9];
                __syncthreads();
                if (total >= KNEG) break;
                E += 192;
            }
            int lo = (E == m1 + 192) ? (m1 - 1) : (E - 192);
            int hi = E;
#pragma unroll
            for (int it = 0; it < 3; ++it) {
                const int mid = (lo + hi) >> 1;
                int c = 0;
#pragma unroll
                for (int j = 0; j < 10; ++j) c += (mv[j] <= mid) ? 1 : 0;
#pragma unroll
                for (int s = 1; s < 64; s <<= 1) c += __shfl_xor(c, s, 64);
                if (lane == 0) misc[6 + wv] = c;
                __syncthreads();
                const int total = misc[6] + misc[7] + misc[8] + misc[9];
                __syncthreads();
                if (total >= KNEG) hi = mid; else lo = mid;
            }
            const float thr = (float)hi + 2.0f * Ranc[arow] + 2.0f * Rmax + 4.0f;

#pragma unroll
            for (int j = 0; j < 10; ++j) {
                const int c = tid + 256 * j;
                if (c < NCHUNK_REAL && (float)mv[j] <= thr) {
                    const int pos = atomicAdd(&misc[0], 1);
                    if (pos < CAND_CAP) candList[pos] = c;
                }
            }
            __syncthreads();
            const int cc = min(misc[0], CAND_CAP);

            const int psub = lane >> 3;
            const int seg  = lane & 7;
            for (int s0 = wv * 4; s0 < cc; s0 += 16) {
                uint4 qp[4];
                int ptv[4];
#pragma unroll
                for (int u = 0; u < 4; ++u) {
                    const int s = s0 + u;
                    const int c = candList[(s < cc) ? s : s0];
                    ptv[u] = c * 8 + psub;
                    qp[u] = ((const uint4*)(pDataQ + (size_t)ptv[u] * 32))[seg];
                }
#pragma unroll
                for (int u = 0; u < 4; ++u) {
                    unsigned int d = sad_u8(qa4.x, qp[u].x, 0u);
                    d = sad_u8(qa4.y, qp[u].y, d);
                    d = sad_u8(qa4.z, qp[u].z, d);
                    d = sad_u8(qa4.w, qp[u].w, d);
                    int di = (int)d;
                    di += __shfl_xor(di, 1, 64);
                    di += __shfl_xor(di, 2, 64);
                    di += __shfl_xor(di, 4, 64);
                    if ((s0 + u) < cc && seg == 0 && (float)di <= thr) {
                        const int pos = atomicAdd(&misc[1], 1);
                        if (pos < PT_CAP) ptList[pos] = ptv[u];
                    }
                }
            }
            __syncthreads();
            const int pc = min(misc[1], PT_CAP);

            const int pt4 = tid >> 2;
            const int qq  = tid & 3;
            float4 av[8];
            {
                const float4* aF4 = (const float4*)(aDataF + (size_t)arow * DIMS) + qq * 8;
#pragma unroll
                for (int q = 0; q < 8; ++q) av[q] = aF4[q];
            }
            for (int base = 0; base < pc; base += 64) {
                const int idx = base + pt4;
                float s01 = 0.f, s23 = 0.f;
                if (idx < pc) {
                    const int pt = ptList[idx];
                    const float4* p4 = (const float4*)(pDataF + (size_t)pt * DIMS) + qq * 8;
#pragma unroll
                    for (int q = 0; q < 8; ++q) {
                        const float4 pv = p4[q];
                        s01 += fabsf(av[q].x - pv.x) + fabsf(av[q].y - pv.y);
                        s23 += fabsf(av[q].z - pv.z) + fabsf(av[q].w - pv.w);
                    }
                }
                float sacc = s01 + s23;
                sacc += __shfl_xor(sacc, 1, 64);
                sacc += __shfl_xor(sacc, 2, 64);
                if (qq == 0 && idx < pc) sDist[idx] = sacc;
            }
            __syncthreads();

            const float dm = ((float*)misc)[14];
            float contrib = 0.f;
            if (pc <= 256) {
                const int i0 = tid;
                const float v = (i0 < pc) ? sDist[i0] : BIGV;
                int r0 = 0;
                int j = 0;
                for (; j + 2 <= pc; j += 2) {
                    const float2 vj = *(const float2*)&sDist[j];
                    r0 += ((vj.x < v) || (vj.x == v && j < i0)) ? 1 : 0;
                    r0 += ((vj.y < v) || (vj.y == v && (j + 1) < i0)) ? 1 : 0;
                }
                if (j < pc) {
                    const float vj = sDist[j];
                    r0 += ((vj < v) || (vj == v && j < i0)) ? 1 : 0;
                }
                if (i0 < pc && r0 < KNEG) contrib = fmaxf(dm - v, 0.f);
            } else {
                const int i0 = tid, i1 = tid + 256, i2 = tid + 512;
                float va = BIGV, vb2 = BIGV, vc = BIGV;
                if (i0 < pc) va = sDist[i0];
                if (i1 < pc) vb2 = sDist[i1];
                if (i2 < pc) vc = sDist[i2];
                int r0 = 0, r1 = 0, r2 = 0;
                for (int j = 0; j < pc; ++j) {
                    const float vj = sDist[j];
                    r0 += (vj < va) || (vj == va && j < i0);
                    r1 += (vj < vb2) || (vj == vb2 && j < i1);
                    r2 += (vj < vc) || (vj == vc && j < i2);
                }
                if (i0 < pc && r0 < KNEG) contrib += fmaxf(dm - va, 0.f);
                if (i1 < pc && r1 < KNEG) contrib += fmaxf(dm - vb2, 0.f);
                if (i2 < pc && r2 < KNEG) contrib += fmaxf(dm - vc, 0.f);
            }
#pragma unroll
            for (int s = 1; s < 64; s <<= 1) contrib += __shfl_xor(contrib, s, 64);
            if (lane == 0) wSum[wv] = contrib;
            __syncthreads();
            if (tid == 0)
                atomicAdd(out, (wSum[0] + wSum[1] + wSum[2] + wSum[3]) *
                               (1.0f / (A_CNT * KNEG)));
        }
    }
}

extern "C" void kernel_launch(void* const* d_in, const int* in_sizes, int n_in,
                              void* d_out, int out_size, void* d_ws, size_t ws_size,
                              hipStream_t stream) {
    const float* out1    = (const float*)d_in[0];
    const float* out2    = (const float*)d_in[1];
    const int*   anchor1 = (const int*)d_in[2];
    const int*   anchor2 = (const int*)d_in[3];
    float* out = (float*)d_out;

    // ws: q1 | q2 | minbuf u16 | R1 | R2 | wsAmax[1024] | wsRmaxPart[1280] | rmax
    unsigned int* q1 = (unsigned int*)d_ws;
    unsigned int* q2 = q1 + (size_t)N_PTS * DIMS / 4;
    unsigned short* minbuf = (unsigned short*)(q2 + (size_t)N_PTS * DIMS / 4);
    float* R1 = (float*)(minbuf + (size_t)2 * A_CNT * NCHUNK);
    float* R2 = R1 + N_PTS;
    float* wsAmax = R2 + N_PTS;
    float* wsRmaxPart = wsAmax + AB_BLOCKS;
    float* rmax = wsRmaxPart + 1280;

    // Coop decision, cached. R10's hard-coded grid=1024 launch silently failed
    // (poison survived): size from the runtime's occupancy answer instead, and
    // verify every step; any failure -> proven 4-dispatch fallback (R9, 208us).
    static int coopMode = -1;   // -1 unknown, 1 use fused, 0 fallback
    static int coopGrid = 0;
    if (coopMode == -1) {
        int dev = 0;
        (void)hipGetDevice(&dev);
        int coopOK = 0;
        (void)hipDeviceGetAttribute(&coopOK, hipDeviceAttributeCooperativeLaunch, dev);
        int cus = 0;
        (void)hipDeviceGetAttribute(&cus, hipDeviceAttributeMultiprocessorCount, dev);
        int nb = 0;
        hipError_t oe = hipOccupancyMaxActiveBlocksPerMultiprocessor(
            &nb, (const void*)fused_kernel, 256, 0);
        if (coopOK && oe == hipSuccess && nb > 0 && cus > 0) {
            long g = (long)nb * (long)cus;
            if (g > 1024) g = 1024;
            coopGrid = (int)g;
            coopMode = (coopGrid >= 256) ? 1 : 0;   // need real parallelism
        } else {
            coopMode = 0;
        }
    }

    if (coopMode == 1) {
        void* args[] = {
            (void*)&out1, (void*)&out2, (void*)&anchor1, (void*)&anchor2,
            (void*)&q1, (void*)&q2, (void*)&minbuf,
            (void*)&R1, (void*)&R2, (void*)&wsAmax, (void*)&wsRmaxPart,
            (void*)&rmax, (void*)&out
        };
        hipError_t err = hipLaunchCooperativeKernel((const void*)fused_kernel,
                                                    dim3(coopGrid), dim3(256),
                                                    args, 0, stream);
        if (err == hipSuccess) return;
        coopMode = 0;   // fall through to the proven chain (and stay there)
    }

    // Fallback: proven 4-dispatch chain.
    hipLaunchKernelGGL(absmax_kernel, dim3(AB_BLOCKS), dim3(256), 0, stream,
                       out1, out2, wsAmax, out);
    hipLaunchKernelGGL(quantR_kernel, dim3(QR_BLOCKS, 2), dim3(256), 0, stream,
                       out1, out2, q1, q2, R1, R2, wsAmax, wsRmaxPart);
    dim3 gridA(NTILES, 16, 2);
    hipLaunchKernelGGL(dist_sad_kernel, gridA, dim3(256), 0, stream,
                       q1, q2, anchor1, anchor2, minbuf, wsRmaxPart, rmax);
    hipLaunchKernelGGL(select_kernel, dim3(2048), dim3(256), 0, stream,
                       out1, out2, q1, q2, anchor1, anchor2, minbuf, R1, R2, rmax, out);
}